// Round 1
// baseline (1054.903 us; speedup 1.0000x reference)
//
#include <hip/hip_runtime.h>
#include <math.h>

#define B 8
#define C 256
#define H 160
#define W 160
#define HW (H*W)
#define HIDDEN 16

// ---------------- k1: Sobel + reductions ----------------
// thread = one pixel (b,h,w); loops over all C channels.
// Outputs: c_sum[b*C+c] = sum over pixels of g  (atomicAdd, pre-zeroed)
//          s_in[b,4,H,W] = {avg_x, max_x, avg_g, max_g}
__global__ __launch_bounds__(256) void k1_sobel_stats(
    const float* __restrict__ x, float* __restrict__ c_sum,
    float* __restrict__ s_in)
{
    const int tid = threadIdx.x;
    const int p   = blockIdx.x * 256 + tid;     // pixel in [0, B*HW)
    const int b   = p / HW;                      // whole block shares b (HW%256==0)
    const int hw  = p % HW;
    const int h   = hw / W;
    const int w   = hw % W;
    const bool up = (h > 0), dn = (h < H-1), lf = (w > 0), rt = (w < W-1);

    const float* xp = x + (size_t)b * C * HW + hw;

    float sum_x = 0.f, max_x = -INFINITY, sum_g = 0.f, max_g = -INFINITY;

    for (int c = 0; c < C; ++c) {
        const float* q = xp + (size_t)c * HW;
        float a0 = (up&&lf) ? q[-W-1] : 0.f;
        float a1 =  up      ? q[-W]   : 0.f;
        float a2 = (up&&rt) ? q[-W+1] : 0.f;
        float b0 =  lf      ? q[-1]   : 0.f;
        float b1 =            q[0];
        float b2 =  rt      ? q[1]    : 0.f;
        float c0 = (dn&&lf) ? q[W-1]  : 0.f;
        float c1 =  dn      ? q[W]    : 0.f;
        float c2 = (dn&&rt) ? q[W+1]  : 0.f;

        // cross-correlation with kx, ky (no flip in XLA conv)
        float gx = 0.25f * ((a0 - a2) + 2.f*(b0 - b2) + (c0 - c2));
        float gy = 0.25f * ((a0 + 2.f*a1 + a2) - (c0 + 2.f*c1 + c2));
        float g  = sqrtf(gx*gx + gy*gy + 1e-12f);

        sum_x += b1;  max_x = fmaxf(max_x, b1);
        sum_g += g;   max_g = fmaxf(max_g, g);

        // wave-level reduce of g over 64 pixels, one atomic per wave
        float gs = g;
        #pragma unroll
        for (int off = 32; off; off >>= 1) gs += __shfl_xor(gs, off, 64);
        if ((tid & 63) == 0) atomicAdd(&c_sum[b*C + c], gs);
    }

    float* sp = s_in + (size_t)b * 4 * HW + hw;
    sp[0]      = sum_x * (1.f/C);
    sp[HW]     = max_x;
    sp[2*HW]   = sum_g * (1.f/C);
    sp[3*HW]   = max_g;
}

// ---------------- k2: channel-gate MLP ----------------
// chanfac[b*C+c] = 1 + softplus(beta) * sigmoid( relu(cv@w1^T) @ w2^T )
__global__ __launch_bounds__(256) void k2_mlp(
    const float* __restrict__ c_sum, const float* __restrict__ w1,
    const float* __restrict__ w2, const float* __restrict__ beta,
    float* __restrict__ chanfac)
{
    __shared__ float cv[B][C];
    __shared__ float hb[B][HIDDEN];
    const int tid = threadIdx.x;   // = channel index

    for (int b = 0; b < B; ++b)
        cv[b][tid] = c_sum[b*C + tid] * (1.f/(float)HW);
    __syncthreads();

    if (tid < B*HIDDEN) {
        int b = tid / HIDDEN, j = tid % HIDDEN;
        float acc = 0.f;
        for (int c = 0; c < C; ++c) acc += cv[b][c] * w1[j*C + c];
        hb[b][j] = fmaxf(acc, 0.f);
    }
    __syncthreads();

    float bt = beta[0];
    float sb = (bt > 20.f) ? bt : log1pf(expf(bt));   // softplus
    for (int b = 0; b < B; ++b) {
        float acc = 0.f;
        #pragma unroll
        for (int j = 0; j < HIDDEN; ++j) acc += hb[b][j] * w2[tid*HIDDEN + j];
        float gate = 1.f / (1.f + expf(-acc));
        chanfac[b*C + tid] = 1.f + sb * gate;
    }
}

// ---------------- k3: 7x7 spatial conv + sigmoid ----------------
// sfac[b*HW+hw] = 1 + softplus(alpha) * sigmoid(conv(s_in)+bias)
__global__ __launch_bounds__(256) void k3_spatial(
    const float* __restrict__ s_in, const float* __restrict__ sw,
    const float* __restrict__ sbias, const float* __restrict__ alpha,
    float* __restrict__ sfac)
{
    __shared__ float wgt[4*49];
    const int tid = threadIdx.x;
    if (tid < 196) wgt[tid] = sw[tid];
    __syncthreads();

    const int p  = blockIdx.x * 256 + tid;   // pixel in [0, B*HW)
    const int b  = p / HW;
    const int hw = p % HW;
    const int h  = hw / W;
    const int w  = hw % W;

    const float* base = s_in + (size_t)b * 4 * HW;
    float acc = 0.f;
    for (int ci = 0; ci < 4; ++ci) {
        const float* pl = base + ci*HW;
        #pragma unroll
        for (int i = 0; i < 7; ++i) {
            int hh = h + i - 3;
            if (hh < 0 || hh >= H) continue;
            const float* row = pl + hh*W;
            const float* wr  = wgt + ci*49 + i*7;
            #pragma unroll
            for (int j = 0; j < 7; ++j) {
                int ww = w + j - 3;
                float v = (ww >= 0 && ww < W) ? row[ww] : 0.f;
                acc = fmaf(wr[j], v, acc);
            }
        }
    }
    float al = alpha[0];
    float sa = (al > 20.f) ? al : log1pf(expf(al));   // softplus
    float sg = 1.f / (1.f + expf(-(acc + sbias[0])));
    sfac[p] = 1.f + sa * sg;
}

// ---------------- k4: elementwise combine (float4) ----------------
__global__ __launch_bounds__(256) void k4_combine(
    const float4* __restrict__ x4, const float* __restrict__ sfac,
    const float* __restrict__ chanfac, float4* __restrict__ out4)
{
    const int i = blockIdx.x * 256 + threadIdx.x;  // float4 index
    const int e  = i * 4;
    const int bc = e / HW;          // b*C + c
    const int hw = e % HW;          // aligned to 4 (HW % 4 == 0)
    const int b  = bc / C;

    const float cf = chanfac[bc];
    const float4 s = *(const float4*)&sfac[b*HW + hw];
    float4 xv = x4[i];
    float4 o;
    o.x = xv.x * s.x * cf;
    o.y = xv.y * s.y * cf;
    o.z = xv.z * s.z * cf;
    o.w = xv.w * s.w * cf;
    out4[i] = o;
}

extern "C" void kernel_launch(void* const* d_in, const int* in_sizes, int n_in,
                              void* d_out, int out_size, void* d_ws, size_t ws_size,
                              hipStream_t stream) {
    const float* x     = (const float*)d_in[0];
    const float* w1    = (const float*)d_in[1];
    const float* w2    = (const float*)d_in[2];
    const float* sw    = (const float*)d_in[3];
    const float* sbias = (const float*)d_in[4];
    const float* alpha = (const float*)d_in[5];
    const float* beta  = (const float*)d_in[6];
    float* out = (float*)d_out;

    float* ws      = (float*)d_ws;
    float* c_sum   = ws;                      // B*C      = 2048
    float* chanfac = ws + 2048;               // B*C      = 2048
    float* s_in    = ws + 4096;               // B*4*HW   = 819200
    float* sfac    = ws + 4096 + B*4*HW;      // B*HW     = 204800

    hipMemsetAsync(c_sum, 0, (size_t)B*C*sizeof(float), stream);

    k1_sobel_stats<<<(B*HW)/256, 256, 0, stream>>>(x, c_sum, s_in);
    k2_mlp<<<1, 256, 0, stream>>>(c_sum, w1, w2, beta, chanfac);
    k3_spatial<<<(B*HW)/256, 256, 0, stream>>>(s_in, sw, sbias, alpha, sfac);
    k4_combine<<<(B*C*HW/4)/256, 256, 0, stream>>>((const float4*)x, sfac, chanfac, (float4*)out);
}